// Round 15
// baseline (228.756 us; speedup 1.0000x reference)
//
#include <hip/hip_runtime.h>

namespace {

constexpr int N_NODES = 50000;
constexpr int E_RAW   = 800000;
constexpr int E_TOT   = E_RAW + N_NODES;   // + self loops
constexpr float SLOPE = 0.2f;
constexpr float EPS_V = 1e-16f;
constexpr int PART_SHIFT = 8;
constexpr int NPART = (N_NODES + 255) >> PART_SHIFT; // 196
constexpr int EPB_S1 = 8192;
constexpr int NB_S1 = (E_TOT + EPB_S1 - 1) / EPB_S1; // 104

typedef short bf16x8 __attribute__((ext_vector_type(8)));
typedef float f32x4 __attribute__((ext_vector_type(4)));

__device__ __forceinline__ unsigned pack_bf16(float a, float b) {
    unsigned ua = __float_as_uint(a);
    unsigned ub = __float_as_uint(b);
    ua += 0x7fffu + ((ua >> 16) & 1u);
    ub += 0x7fffu + ((ub >> 16) & 1u);
    return (ua >> 16) | (ub & 0xffff0000u);
}
__device__ __forceinline__ unsigned short bf16r(float a) {
    unsigned ua = __float_as_uint(a);
    ua += 0x7fffu + ((ua >> 16) & 1u);
    return (unsigned short)(ua >> 16);
}
__device__ __forceinline__ float blo(unsigned u) { return __uint_as_float(u << 16); }
__device__ __forceinline__ float bhi(unsigned u) { return __uint_as_float(u & 0xffff0000u); }
__device__ __forceinline__ float lrelu(float v) { return v > 0.f ? v : SLOPE * v; }

// ---- W prep: Wt[n][k] = bf16(W[k][n]) AND attention fold-in:
// Wab[j][k] = bf16( sum_c W[k][head(j)*C + c] * a_{src|dst}[head(j)][c] )
// (j = 0..3 src heads, 4..7 dst heads; cols 8..15 zero). One block per layer.
__global__ __launch_bounds__(256) void wtprep_k(
    const float* __restrict__ W0, const float* __restrict__ W1,
    const float* __restrict__ W2,
    const float* __restrict__ as0, const float* __restrict__ ad0,
    const float* __restrict__ as1, const float* __restrict__ ad1,
    const float* __restrict__ as2, const float* __restrict__ ad2,
    unsigned short* __restrict__ Wt0, unsigned short* __restrict__ Wt1,
    unsigned short* __restrict__ Wt2,
    unsigned short* __restrict__ Wab0, unsigned short* __restrict__ Wab1,
    unsigned short* __restrict__ Wab2)
{
    const int b = blockIdx.x;
    const float* W  = b == 0 ? W0  : (b == 1 ? W1  : W2);
    const float* av = b == 0 ? as0 : (b == 1 ? as1 : as2);
    const float* dv = b == 0 ? ad0 : (b == 1 ? ad1 : ad2);
    unsigned short* Wt  = b == 0 ? Wt0  : (b == 1 ? Wt1  : Wt2);
    unsigned short* Wab = b == 0 ? Wab0 : (b == 1 ? Wab1 : Wab2);
    const bool h4 = (b != 2);
    __shared__ float Ws[128 * 128];
    const int t = threadIdx.x;
    #pragma unroll
    for (int i = 0; i < 16; ++i)
        ((float4*)Ws)[t + 256 * i] = ((const float4*)W)[t + 256 * i];
    __syncthreads();
    // Wt (bf16 transpose)
    #pragma unroll
    for (int i = 0; i < 8; ++i) {
        int g = t + 256 * i;
        int n = g >> 4, c = g & 15;
        uint4 u;
        unsigned um[4];
        #pragma unroll
        for (int j = 0; j < 4; ++j) {
            float lo = Ws[(c * 8 + 2 * j) * 128 + n];
            float hi = Ws[(c * 8 + 2 * j + 1) * 128 + n];
            um[j] = pack_bf16(lo, hi);
        }
        u.x = um[0]; u.y = um[1]; u.z = um[2]; u.w = um[3];
        ((uint4*)Wt)[g] = u;
    }
    // Wab
    for (int i = t; i < 16 * 128; i += 256) Wab[i] = 0;
    __syncthreads();
    for (int idx = t; idx < 1024; idx += 256) {
        int k = idx >> 3, j = idx & 7;
        float d = 0.f;
        if (h4) {
            const float* a = (j < 4) ? av : dv;
            int h = j & 3;
            #pragma unroll 4
            for (int c = 0; c < 32; ++c)
                d = fmaf(Ws[k * 128 + h * 32 + c], a[h * 32 + c], d);
        } else {
            if (j == 0) {
                #pragma unroll 4
                for (int c = 0; c < 128; ++c) d = fmaf(Ws[k * 128 + c], av[c], d);
            } else if (j == 1) {
                #pragma unroll 4
                for (int c = 0; c < 128; ++c) d = fmaf(Ws[k * 128 + c], dv[c], d);
            }
        }
        if (j < 2 || h4) Wab[j * 128 + k] = bf16r(d);
    }
}

// ---- MFMA GEMM: h = X @ W; s/d via extra MFMA column block (X @ Wab) ----
template<int H, bool IN32>
__global__ __launch_bounds__(256) void gemm_mfma_k(
    const void* __restrict__ Xin, const unsigned short* __restrict__ Wt,
    const unsigned short* __restrict__ Wab,
    unsigned short* __restrict__ Hb, int nrows,
    float* __restrict__ sb, float* __restrict__ db)
{
    __shared__ unsigned short Wts[128 * 128];
    const int t = threadIdx.x;
    const int row0 = blockIdx.x * 128;

    {
        const uint4* wv = (const uint4*)Wt;
        #pragma unroll
        for (int i = 0; i < 8; ++i) {
            int g = t + 256 * i;
            int n = g >> 4, c = g & 15;
            *(uint4*)&Wts[n * 128 + ((c ^ (n & 7)) << 3)] = wv[g];
        }
    }
    __syncthreads();

    const int lane = t & 63;
    const int w = t >> 6;           // wave: rows w*32 .. w*32+31
    const int lr = lane & 15;       // row-in-frag (A) / col-in-frag (B,D)
    const int lk = lane >> 4;       // k-subchunk / D row group

    f32x4 acc[2][8];
    f32x4 accsd[2];
    #pragma unroll
    for (int rf = 0; rf < 2; ++rf) {
        accsd[rf] = (f32x4)(0.f);
        #pragma unroll
        for (int cf = 0; cf < 8; ++cf)
            acc[rf][cf] = (f32x4)(0.f);
    }

    int arow[2];
    #pragma unroll
    for (int rf = 0; rf < 2; ++rf) {
        int r = row0 + w * 32 + rf * 16 + lr;
        arow[rf] = r < nrows ? r : nrows - 1;
    }

    #pragma unroll
    for (int ks = 0; ks < 4; ++ks) {
        bf16x8 av[2], bv[8];
        #pragma unroll
        for (int rf = 0; rf < 2; ++rf) {
            if (IN32) {
                const float* Xf = (const float*)Xin;
                float4 f0 = *(const float4*)(Xf + (size_t)arow[rf] * 128 + (ks * 4 + lk) * 8);
                float4 f1 = *(const float4*)(Xf + (size_t)arow[rf] * 128 + (ks * 4 + lk) * 8 + 4);
                unsigned u0 = pack_bf16(f0.x, f0.y), u1 = pack_bf16(f0.z, f0.w);
                unsigned u2 = pack_bf16(f1.x, f1.y), u3 = pack_bf16(f1.z, f1.w);
                uint4 uu = make_uint4(u0, u1, u2, u3);
                av[rf] = *(bf16x8*)&uu;
            } else {
                const unsigned short* Xb = (const unsigned short*)Xin;
                av[rf] = *(const bf16x8*)(Xb + (size_t)arow[rf] * 128 + (ks * 4 + lk) * 8);
            }
        }
        #pragma unroll
        for (int cf = 0; cf < 8; ++cf) {
            int col = cf * 16 + lr;
            bv[cf] = *(const bf16x8*)&Wts[col * 128 + (((ks * 4 + lk) ^ (col & 7)) << 3)];
        }
        bf16x8 bsd = *(const bf16x8*)(Wab + lr * 128 + (ks * 4 + lk) * 8);
        #pragma unroll
        for (int rf = 0; rf < 2; ++rf) {
            #pragma unroll
            for (int cf = 0; cf < 8; ++cf)
                acc[rf][cf] = __builtin_amdgcn_mfma_f32_16x16x32_bf16(
                    av[rf], bv[cf], acc[rf][cf], 0, 0, 0);
            accsd[rf] = __builtin_amdgcn_mfma_f32_16x16x32_bf16(
                av[rf], bsd, accsd[rf], 0, 0, 0);
        }
    }

    // epilogue: Hb bf16 store + direct s/d store (D layout: col=lr, row=lk*4+reg)
    #pragma unroll
    for (int rf = 0; rf < 2; ++rf) {
        #pragma unroll
        for (int reg = 0; reg < 4; ++reg) {
            const int gr = row0 + w * 32 + rf * 16 + lk * 4 + reg;
            if (gr >= nrows) continue;
            #pragma unroll
            for (int cf = 0; cf < 8; ++cf)
                Hb[(size_t)gr * 128 + cf * 16 + lr] = bf16r(acc[rf][cf][reg]);
            float v = accsd[rf][reg];
            if (H == 4) {
                if (lr < 4)      sb[gr * 4 + lr] = v;
                else if (lr < 8) db[gr * 4 + (lr - 4)] = v;
            } else {
                if (lr == 0)      sb[gr] = v;
                else if (lr == 1) db[gr] = v;
            }
        }
    }
}

__device__ __forceinline__ void edge_endpoints(const int* __restrict__ ei, int e,
                                               int& src, int& dst)
{
    if (e < E_RAW) { src = ei[e]; dst = ei[E_RAW + e]; }
    else           { src = e - E_RAW; dst = src; }
}

__device__ __forceinline__ int block_incl_scan_256(int x, int* wsum) {
    int lane = threadIdx.x & 63, wid = threadIdx.x >> 6;
    #pragma unroll
    for (int off = 1; off < 64; off <<= 1) {
        int y = __shfl_up(x, off, 64);
        if (lane >= off) x += y;
    }
    if (lane == 63) wsum[wid] = x;
    __syncthreads();
    int add = 0;
    #pragma unroll
    for (int w = 0; w < 4; ++w) if (w < wid) add += wsum[w];
    return x + add;
}

// ============ CSR build (partition-level; once per call) ============
__global__ __launch_bounds__(256) void pcount_k(
    const int* __restrict__ ei, int* __restrict__ pc)
{
    __shared__ int h[NPART];
    const int t = threadIdx.x;
    const int e0 = blockIdx.x * EPB_S1;
    int ne = E_TOT - e0; if (ne > EPB_S1) ne = EPB_S1;
    for (int i = t; i < NPART; i += 256) h[i] = 0;
    __syncthreads();
    for (int i = t; i < ne; i += 256) {
        int src, dst;
        edge_endpoints(ei, e0 + i, src, dst);
        atomicAdd(&h[dst >> PART_SHIFT], 1);
    }
    __syncthreads();
    for (int i = t; i < NPART; i += 256)
        if (h[i]) atomicAdd(&pc[i], h[i]);
}

__global__ __launch_bounds__(256) void pscan_k(
    const int* __restrict__ pc, int* __restrict__ pbase, int* __restrict__ pcur)
{
    __shared__ int wsum[4];
    const int t = threadIdx.x;
    int x = (t < NPART) ? pc[t] : 0;
    int incl = block_incl_scan_256(x, wsum);
    if (t < NPART) { pbase[t] = incl - x; pcur[t] = incl - x; }
    if (t == NPART - 1) pbase[NPART] = incl;   // == E_TOT
}

__global__ __launch_bounds__(256) void part_scatter_k(
    const int* __restrict__ ei, int* __restrict__ pcur, unsigned* __restrict__ pbuf)
{
    __shared__ unsigned code[EPB_S1];   // 32 KB
    __shared__ int hist[NPART];
    __shared__ int hbase[NPART];
    const int t = threadIdx.x;
    const int e0 = blockIdx.x * EPB_S1;
    int ne = E_TOT - e0; if (ne > EPB_S1) ne = EPB_S1;

    for (int p = t; p < NPART; p += 256) hist[p] = 0;
    __syncthreads();
    for (int i = t; i < ne; i += 256) {
        int src, dst;
        edge_endpoints(ei, e0 + i, src, dst);
        unsigned c = ((unsigned)dst << 16) | (unsigned)src;
        code[i] = c;
        atomicAdd(&hist[dst >> PART_SHIFT], 1);
    }
    __syncthreads();
    for (int p = t; p < NPART; p += 256) {
        int hcnt = hist[p];
        hbase[p] = hcnt > 0 ? atomicAdd(&pcur[p], hcnt) : 0;
        hist[p] = 0;   // reuse as local cursor
    }
    __syncthreads();
    for (int i = t; i < ne; i += 256) {
        unsigned c = code[i];
        int p = c >> (16 + PART_SHIFT);
        int loc = atomicAdd(&hist[p], 1);
        pbuf[hbase[p] + loc] = c;
    }
}

__global__ __launch_bounds__(256) void part_to_csr2_k(
    const int* __restrict__ pbase, const unsigned* __restrict__ pbuf,
    int* __restrict__ rp, unsigned short* __restrict__ csr16)
{
    const int p = blockIdx.x;
    const int t = threadIdx.x;
    const int n0 = p << PART_SHIFT;
    const int start = pbase[p], endp = pbase[p + 1];

    __shared__ int hist[256];
    __shared__ int base[256];
    __shared__ int wsum[4];
    hist[t] = 0;
    __syncthreads();
    for (int i = start + t; i < endp; i += 256)
        atomicAdd(&hist[(pbuf[i] >> 16) & 255], 1);
    __syncthreads();
    int x = hist[t];
    int incl = block_incl_scan_256(x, wsum);
    base[t] = start + incl - x;
    int n = n0 + t;
    if (n < N_NODES) rp[n] = base[t];
    if (p == NPART - 1 && t == 0) rp[N_NODES] = E_TOT;
    hist[t] = 0;
    __syncthreads();
    for (int i = start + t; i < endp; i += 256) {
        unsigned c = pbuf[i];
        int local = (c >> 16) & 255;
        int pos = base[local] + atomicAdd(&hist[local], 1);
        csr16[pos] = (unsigned short)(c & 0xffffu);
    }
}

// ============ fused per-destination GAT aggregation ============
// ONE WAVE PER NODE, zero barriers. 4-wide-unrolled gather main loop.
template<int H, bool RELU, bool OUTB>
__global__ __launch_bounds__(256) void gat_fused_k(
    const int* __restrict__ rp, const unsigned short* __restrict__ csr16,
    const unsigned short* __restrict__ Hb, const float* __restrict__ sb,
    const float* __restrict__ db, const float* __restrict__ bias,
    void* __restrict__ outv)
{
    constexpr int C = 128 / H;
    const int lane = threadIdx.x & 63;
    const int n = blockIdx.x * 4 + (threadIdx.x >> 6);
    if (n >= N_NODES) return;
    const int beg = rp[n], end = rp[n + 1];
    const int deg = end - beg;

    const int f    = lane & 15;          // channel group: f*8 .. f*8+7
    const int slot = lane >> 4;          // 4 edge slots
    const int hf   = (f * 8) / C;        // head for this channel group

    float dn[H];
    #pragma unroll
    for (int h = 0; h < H; ++h) dn[h] = db[n * H + h];

    float a0=0.f,a1=0.f,a2=0.f,a3=0.f,a4=0.f,a5=0.f,a6=0.f,a7=0.f;
    float den = 0.f;

    if (deg <= 64) {
        const bool act = lane < deg;
        int s = 0;
        if (act) s = csr16[beg + lane];
        float v[H];
        if (H == 4) {
            float4 s4 = ((const float4*)sb)[s];
            v[0] = lrelu(s4.x + dn[0]); v[1] = lrelu(s4.y + dn[1]);
            v[2] = lrelu(s4.z + dn[2]); v[3] = lrelu(s4.w + dn[3]);
        } else {
            v[0] = lrelu(sb[s] + dn[0]);
        }
        float mh[H];
        #pragma unroll
        for (int h = 0; h < H; ++h) mh[h] = act ? v[h] : -3.0e38f;
        #pragma unroll
        for (int off = 32; off >= 1; off >>= 1)
            #pragma unroll
            for (int h = 0; h < H; ++h)
                mh[h] = fmaxf(mh[h], __shfl_xor(mh[h], off, 64));
        float p[H];
        #pragma unroll
        for (int h = 0; h < H; ++h) p[h] = __expf(v[h] - mh[h]);

        const int iters = (deg + 3) >> 2;
        int it = 0;
        for (; it + 4 <= iters; it += 4) {
            const int jj0 = slot + it * 4;
            const int jj1 = jj0 + 4, jj2 = jj0 + 8, jj3 = jj0 + 12;
            const bool on3 = jj3 < deg;
            const int jc3 = on3 ? jj3 : 0;
            int sj0 = __shfl(s, jj0, 64), sj1 = __shfl(s, jj1, 64);
            int sj2 = __shfl(s, jj2, 64), sj3 = __shfl(s, jc3, 64);
            float pj0, pj1, pj2, pj3;
            if (H == 4) {
                float q00=__shfl(p[0],jj0,64), q01=__shfl(p[1],jj0,64), q02=__shfl(p[2],jj0,64), q03=__shfl(p[3],jj0,64);
                float q10=__shfl(p[0],jj1,64), q11=__shfl(p[1],jj1,64), q12=__shfl(p[2],jj1,64), q13=__shfl(p[3],jj1,64);
                float q20=__shfl(p[0],jj2,64), q21=__shfl(p[1],jj2,64), q22=__shfl(p[2],jj2,64), q23=__shfl(p[3],jj2,64);
                float q30=__shfl(p[0],jc3,64), q31=__shfl(p[1],jc3,64), q32=__shfl(p[2],jc3,64), q33=__shfl(p[3],jc3,64);
                pj0 = hf == 0 ? q00 : (hf == 1 ? q01 : (hf == 2 ? q02 : q03));
                pj1 = hf == 0 ? q10 : (hf == 1 ? q11 : (hf == 2 ? q12 : q13));
                pj2 = hf == 0 ? q20 : (hf == 1 ? q21 : (hf == 2 ? q22 : q23));
                pj3 = hf == 0 ? q30 : (hf == 1 ? q31 : (hf == 2 ? q32 : q33));
            } else {
                pj0 = __shfl(p[0], jj0, 64); pj1 = __shfl(p[0], jj1, 64);
                pj2 = __shfl(p[0], jj2, 64); pj3 = __shfl(p[0], jc3, 64);
            }
            pj3 = on3 ? pj3 : 0.f;
            uint4 hv0 = *(const uint4*)(Hb + (size_t)sj0 * 128 + f * 8);
            uint4 hv1 = *(const uint4*)(Hb + (size_t)sj1 * 128 + f * 8);
            uint4 hv2 = *(const uint4*)(Hb + (size_t)sj2 * 128 + f * 8);
            uint4 hv3 = *(const uint4*)(Hb + (size_t)sj3 * 128 + f * 8);
            den += pj0 + pj1 + pj2 + pj3;
            a0 = fmaf(pj0, blo(hv0.x), a0);  a1 = fmaf(pj0, bhi(hv0.x), a1);
            a2 = fmaf(pj0, blo(hv0.y), a2);  a3 = fmaf(pj0, bhi(hv0.y), a3);
            a4 = fmaf(pj0, blo(hv0.z), a4);  a5 = fmaf(pj0, bhi(hv0.z), a5);
            a6 = fmaf(pj0, blo(hv0.w), a6);  a7 = fmaf(pj0, bhi(hv0.w), a7);
            a0 = fmaf(pj1, blo(hv1.x), a0);  a1 = fmaf(pj1, bhi(hv1.x), a1);
            a2 = fmaf(pj1, blo(hv1.y), a2);  a3 = fmaf(pj1, bhi(hv1.y), a3);
            a4 = fmaf(pj1, blo(hv1.z), a4);  a5 = fmaf(pj1, bhi(hv1.z), a5);
            a6 = fmaf(pj1, blo(hv1.w), a6);  a7 = fmaf(pj1, bhi(hv1.w), a7);
            a0 = fmaf(pj2, blo(hv2.x), a0);  a1 = fmaf(pj2, bhi(hv2.x), a1);
            a2 = fmaf(pj2, blo(hv2.y), a2);  a3 = fmaf(pj2, bhi(hv2.y), a3);
            a4 = fmaf(pj2, blo(hv2.z), a4);  a5 = fmaf(pj2, bhi(hv2.z), a5);
            a6 = fmaf(pj2, blo(hv2.w), a6);  a7 = fmaf(pj2, bhi(hv2.w), a7);
            a0 = fmaf(pj3, blo(hv3.x), a0);  a1 = fmaf(pj3, bhi(hv3.x), a1);
            a2 = fmaf(pj3, blo(hv3.y), a2);  a3 = fmaf(pj3, bhi(hv3.y), a3);
            a4 = fmaf(pj3, blo(hv3.z), a4);  a5 = fmaf(pj3, bhi(hv3.z), a5);
            a6 = fmaf(pj3, blo(hv3.w), a6);  a7 = fmaf(pj3, bhi(hv3.w), a7);
        }
        for (; it < iters; ++it) {
            const int jj = slot + it * 4;
            const bool on = jj < deg;
            const int jc = on ? jj : 0;
            int sj = __shfl(s, jc, 64);
            float pj;
            if (H == 4) {
                float q0 = __shfl(p[0], jc, 64);
                float q1 = __shfl(p[1], jc, 64);
                float q2 = __shfl(p[2], jc, 64);
                float q3 = __shfl(p[3], jc, 64);
                pj = hf == 0 ? q0 : (hf == 1 ? q1 : (hf == 2 ? q2 : q3));
            } else {
                pj = __shfl(p[0], jc, 64);
            }
            pj = on ? pj : 0.f;
            den += pj;
            uint4 hv = *(const uint4*)(Hb + (size_t)sj * 128 + f * 8);
            a0 = fmaf(pj, blo(hv.x), a0);  a1 = fmaf(pj, bhi(hv.x), a1);
            a2 = fmaf(pj, blo(hv.y), a2);  a3 = fmaf(pj, bhi(hv.y), a3);
            a4 = fmaf(pj, blo(hv.z), a4);  a5 = fmaf(pj, bhi(hv.z), a5);
            a6 = fmaf(pj, blo(hv.w), a6);  a7 = fmaf(pj, bhi(hv.w), a7);
        }
    } else {
        float mh[H];
        #pragma unroll
        for (int h = 0; h < H; ++h) mh[h] = -3.0e38f;
        for (int i = beg + lane; i < end; i += 64) {
            int s = csr16[i];
            if (H == 4) {
                float4 s4 = ((const float4*)sb)[s];
                mh[0] = fmaxf(mh[0], lrelu(s4.x + dn[0]));
                mh[1] = fmaxf(mh[1], lrelu(s4.y + dn[1]));
                mh[2] = fmaxf(mh[2], lrelu(s4.z + dn[2]));
                mh[3] = fmaxf(mh[3], lrelu(s4.w + dn[3]));
            } else {
                mh[0] = fmaxf(mh[0], lrelu(sb[s] + dn[0]));
            }
        }
        #pragma unroll
        for (int off = 32; off >= 1; off >>= 1)
            #pragma unroll
            for (int h = 0; h < H; ++h)
                mh[h] = fmaxf(mh[h], __shfl_xor(mh[h], off, 64));
        float mhf = (H == 1) ? mh[0]
                  : (hf == 0 ? mh[0] : hf == 1 ? mh[1] : hf == 2 ? mh[2] : mh[3]);
        float dnf = (H == 1) ? dn[0]
                  : (hf == 0 ? dn[0] : hf == 1 ? dn[1] : hf == 2 ? dn[2] : dn[3]);
        for (int jj = slot; jj < deg; jj += 4) {
            int sj = csr16[beg + jj];
            float pj = __expf(lrelu(sb[sj * H + hf] + dnf) - mhf);
            den += pj;
            uint4 hv = *(const uint4*)(Hb + (size_t)sj * 128 + f * 8);
            a0 = fmaf(pj, blo(hv.x), a0);  a1 = fmaf(pj, bhi(hv.x), a1);
            a2 = fmaf(pj, blo(hv.y), a2);  a3 = fmaf(pj, bhi(hv.y), a3);
            a4 = fmaf(pj, blo(hv.z), a4);  a5 = fmaf(pj, bhi(hv.z), a5);
            a6 = fmaf(pj, blo(hv.w), a6);  a7 = fmaf(pj, bhi(hv.w), a7);
        }
    }

    #pragma unroll
    for (int off = 16; off < 64; off <<= 1) {
        a0 += __shfl_xor(a0, off, 64); a1 += __shfl_xor(a1, off, 64);
        a2 += __shfl_xor(a2, off, 64); a3 += __shfl_xor(a3, off, 64);
        a4 += __shfl_xor(a4, off, 64); a5 += __shfl_xor(a5, off, 64);
        a6 += __shfl_xor(a6, off, 64); a7 += __shfl_xor(a7, off, 64);
        den += __shfl_xor(den, off, 64);
    }
    if (lane < 16) {
        float inv = 1.f / (den + EPS_V);
        float4 ba = *(const float4*)(bias + f * 8);
        float4 bb = *(const float4*)(bias + f * 8 + 4);
        float o0 = a0 * inv + ba.x, o1 = a1 * inv + ba.y;
        float o2 = a2 * inv + ba.z, o3 = a3 * inv + ba.w;
        float o4 = a4 * inv + bb.x, o5 = a5 * inv + bb.y;
        float o6 = a6 * inv + bb.z, o7 = a7 * inv + bb.w;
        if (RELU) {
            o0 = fmaxf(o0, 0.f); o1 = fmaxf(o1, 0.f);
            o2 = fmaxf(o2, 0.f); o3 = fmaxf(o3, 0.f);
            o4 = fmaxf(o4, 0.f); o5 = fmaxf(o5, 0.f);
            o6 = fmaxf(o6, 0.f); o7 = fmaxf(o7, 0.f);
        }
        if (OUTB) {
            unsigned short* ob = (unsigned short*)outv;
            uint4 u;
            u.x = pack_bf16(o0, o1); u.y = pack_bf16(o2, o3);
            u.z = pack_bf16(o4, o5); u.w = pack_bf16(o6, o7);
            *(uint4*)(ob + (size_t)n * 128 + f * 8) = u;
        } else {
            float* op = (float*)outv + (size_t)n * 128 + f * 8;
            *(float4*)(op)     = make_float4(o0, o1, o2, o3);
            *(float4*)(op + 4) = make_float4(o4, o5, o6, o7);
        }
    }
}

template<int H, bool IN32, bool RELU, bool OUTB>
void run_layer(const void* xin, const unsigned short* Wt, const unsigned short* Wab,
               const float* bias, const int* rp, const unsigned short* csr16,
               unsigned short* hbuf, void* outv, float* sb, float* db,
               hipStream_t stream)
{
    gemm_mfma_k<H, IN32><<<(N_NODES + 127) / 128, 256, 0, stream>>>(
        xin, Wt, Wab, hbuf, N_NODES, sb, db);
    gat_fused_k<H, RELU, OUTB><<<(N_NODES + 3) / 4, 256, 0, stream>>>(
        rp, csr16, hbuf, sb, db, bias, outv);
}

} // namespace

extern "C" void kernel_launch(void* const* d_in, const int* in_sizes, int n_in,
                              void* d_out, int out_size, void* d_ws, size_t ws_size,
                              hipStream_t stream)
{
    (void)in_sizes; (void)n_in; (void)out_size; (void)ws_size;
    const float* x   = (const float*)d_in[0];
    const int*   ei  = (const int*)d_in[1];
    const float* W0  = (const float*)d_in[2];
    const float* as0 = (const float*)d_in[3];
    const float* ad0 = (const float*)d_in[4];
    const float* b0  = (const float*)d_in[5];
    const float* W1  = (const float*)d_in[6];
    const float* as1 = (const float*)d_in[7];
    const float* ad1 = (const float*)d_in[8];
    const float* b1  = (const float*)d_in[9];
    const float* W2  = (const float*)d_in[10];
    const float* as2 = (const float*)d_in[11];
    const float* ad2 = (const float*)d_in[12];
    const float* b2  = (const float*)d_in[13];
    float* out = (float*)d_out;

    char* p = (char*)d_ws;
    unsigned short* Hb  = (unsigned short*)p; p += (size_t)N_NODES * 128 * 2;  // bf16 h
    unsigned short* Xb1 = (unsigned short*)p; p += (size_t)N_NODES * 128 * 2;  // bf16 x1
    unsigned short* Xb2 = (unsigned short*)p; p += (size_t)N_NODES * 128 * 2;  // bf16 x2
    unsigned short* Wt0 = (unsigned short*)p; p += 128 * 128 * 2;
    unsigned short* Wt1 = (unsigned short*)p; p += 128 * 128 * 2;
    unsigned short* Wt2 = (unsigned short*)p; p += 128 * 128 * 2;
    unsigned short* Wab0 = (unsigned short*)p; p += 16 * 128 * 2;
    unsigned short* Wab1 = (unsigned short*)p; p += 16 * 128 * 2;
    unsigned short* Wab2 = (unsigned short*)p; p += 16 * 128 * 2;
    float* sb      = (float*)p;  p += (size_t)N_NODES * 4 * 4;
    float* db      = (float*)p;  p += (size_t)N_NODES * 4 * 4;
    int*   rp      = (int*)p;    p += (size_t)(N_NODES + 1) * 4;
    int*   pc      = (int*)p;    p += (size_t)NPART * 4;
    int*   pbase   = (int*)p;    p += (size_t)(NPART + 1) * 4;
    int*   pcur    = (int*)p;    p += (size_t)NPART * 4;
    unsigned* pbuf = (unsigned*)p; p += (size_t)E_TOT * 4;
    unsigned short* csr16 = (unsigned short*)p; p += (size_t)E_TOT * 2;

    // ---- one-time prep: W transposes + attn fold-in + partition CSR build ----
    wtprep_k<<<3, 256, 0, stream>>>(W0, W1, W2, as0, ad0, as1, ad1, as2, ad2,
                                    Wt0, Wt1, Wt2, Wab0, Wab1, Wab2);
    hipMemsetAsync(pc, 0, (size_t)NPART * 4, stream);
    pcount_k<<<NB_S1, 256, 0, stream>>>(ei, pc);
    pscan_k<<<1, 256, 0, stream>>>(pc, pbase, pcur);
    part_scatter_k<<<NB_S1, 256, 0, stream>>>(ei, pcur, pbuf);
    part_to_csr2_k<<<NPART, 256, 0, stream>>>(pbase, pbuf, rp, csr16);

    // Layer 0: x(fp32 direct) -> h(Hb); agg -> Xb1 (bf16, ReLU)
    run_layer<4, true,  true,  true >(x,   Wt0, Wab0, b0, rp, csr16, Hb, Xb1, sb, db, stream);
    // Layer 1: Xb1 -> h(Hb); agg -> Xb2 (bf16, ReLU)
    run_layer<4, false, true,  true >(Xb1, Wt1, Wab1, b1, rp, csr16, Hb, Xb2, sb, db, stream);
    // Layer 2 (H=1): Xb2 -> h(Hb); agg -> out (fp32, no ReLU)
    run_layer<1, false, false, false>(Xb2, Wt2, Wab2, b2, rp, csr16, Hb, out, sb, db, stream);
}

// Round 16
// 194.234 us; speedup vs baseline: 1.1777x; 1.1777x over previous
//
#include <hip/hip_runtime.h>

namespace {

constexpr int N_NODES = 50000;
constexpr int E_RAW   = 800000;
constexpr int E_TOT   = E_RAW + N_NODES;   // + self loops
constexpr float SLOPE = 0.2f;
constexpr float EPS_V = 1e-16f;
constexpr int PART_SHIFT = 8;
constexpr int NPART = (N_NODES + 255) >> PART_SHIFT; // 196
constexpr int PCAP  = 6144;                 // padded partition slot (exp 4337, sigma 66)
constexpr int EPB_S1 = 8192;
constexpr int NB_S1 = (E_TOT + EPB_S1 - 1) / EPB_S1; // 104

typedef short bf16x8 __attribute__((ext_vector_type(8)));
typedef float f32x4 __attribute__((ext_vector_type(4)));

__device__ __forceinline__ unsigned pack_bf16(float a, float b) {
    unsigned ua = __float_as_uint(a);
    unsigned ub = __float_as_uint(b);
    ua += 0x7fffu + ((ua >> 16) & 1u);
    ub += 0x7fffu + ((ub >> 16) & 1u);
    return (ua >> 16) | (ub & 0xffff0000u);
}
__device__ __forceinline__ unsigned short bf16r(float a) {
    unsigned ua = __float_as_uint(a);
    ua += 0x7fffu + ((ua >> 16) & 1u);
    return (unsigned short)(ua >> 16);
}
__device__ __forceinline__ float blo(unsigned u) { return __uint_as_float(u << 16); }
__device__ __forceinline__ float bhi(unsigned u) { return __uint_as_float(u & 0xffff0000u); }
__device__ __forceinline__ float lrelu(float v) { return v > 0.f ? v : SLOPE * v; }

__device__ __forceinline__ void edge_endpoints(const int* __restrict__ ei, int e,
                                               int& src, int& dst)
{
    if (e < E_RAW) { src = ei[e]; dst = ei[E_RAW + e]; }
    else           { src = e - E_RAW; dst = src; }
}

__device__ __forceinline__ int block_incl_scan_256(int x, int* wsum) {
    int lane = threadIdx.x & 63, wid = threadIdx.x >> 6;
    #pragma unroll
    for (int off = 1; off < 64; off <<= 1) {
        int y = __shfl_up(x, off, 64);
        if (lane >= off) x += y;
    }
    if (lane == 63) wsum[wid] = x;
    __syncthreads();
    int add = 0;
    #pragma unroll
    for (int w = 0; w < 4; ++w) if (w < wid) add += wsum[w];
    return x + add;
}

// ---- merged prep: blocks 0..2 = W transpose (bf16); blocks 3.. = partition
// scatter of packed (dst<<16|src) codes into padded partition slots (p*PCAP).
__global__ __launch_bounds__(256) void prep_k(
    const float* __restrict__ W0, const float* __restrict__ W1,
    const float* __restrict__ W2,
    unsigned short* __restrict__ Wt0, unsigned short* __restrict__ Wt1,
    unsigned short* __restrict__ Wt2,
    const int* __restrict__ ei, int* __restrict__ pcnt,
    unsigned* __restrict__ pbuf)
{
    __shared__ float Ws[128 * 128];          // 64 KB (wtprep blocks)
    __shared__ unsigned code[EPB_S1];        // 32 KB (scatter blocks)
    __shared__ int hist[NPART];
    __shared__ int hbase[NPART];
    const int t = threadIdx.x;
    const int b = blockIdx.x;

    if (b < 3) {
        const float* W = b == 0 ? W0 : (b == 1 ? W1 : W2);
        unsigned short* Wt = b == 0 ? Wt0 : (b == 1 ? Wt1 : Wt2);
        #pragma unroll
        for (int i = 0; i < 16; ++i)
            ((float4*)Ws)[t + 256 * i] = ((const float4*)W)[t + 256 * i];
        __syncthreads();
        #pragma unroll
        for (int i = 0; i < 8; ++i) {
            int g = t + 256 * i;
            int n = g >> 4, c = g & 15;
            uint4 u;
            unsigned um[4];
            #pragma unroll
            for (int j = 0; j < 4; ++j) {
                float lo = Ws[(c * 8 + 2 * j) * 128 + n];
                float hi = Ws[(c * 8 + 2 * j + 1) * 128 + n];
                um[j] = pack_bf16(lo, hi);
            }
            u.x = um[0]; u.y = um[1]; u.z = um[2]; u.w = um[3];
            ((uint4*)Wt)[g] = u;
        }
        return;
    }

    const int e0 = (b - 3) * EPB_S1;
    int ne = E_TOT - e0; if (ne > EPB_S1) ne = EPB_S1;
    for (int p = t; p < NPART; p += 256) hist[p] = 0;
    __syncthreads();
    for (int i = t; i < ne; i += 256) {
        int src, dst;
        edge_endpoints(ei, e0 + i, src, dst);
        unsigned c = ((unsigned)dst << 16) | (unsigned)src;
        code[i] = c;
        atomicAdd(&hist[dst >> PART_SHIFT], 1);
    }
    __syncthreads();
    for (int p = t; p < NPART; p += 256) {
        int hcnt = hist[p];
        hbase[p] = hcnt > 0 ? (p * PCAP + atomicAdd(&pcnt[p], hcnt)) : 0;
        hist[p] = 0;   // reuse as local cursor
    }
    __syncthreads();
    for (int i = t; i < ne; i += 256) {
        unsigned c = code[i];
        int p = c >> (16 + PART_SHIFT);
        int loc = atomicAdd(&hist[p], 1);
        pbuf[hbase[p] + loc] = c;
    }
}

// ---- per-partition node histogram + local scan -> rp/rpe, LDS-cursor scatter ----
__global__ __launch_bounds__(256) void part_to_csr2_k(
    const int* __restrict__ pcnt, const unsigned* __restrict__ pbuf,
    int* __restrict__ rp, int* __restrict__ rpe, unsigned short* __restrict__ csr16)
{
    const int p = blockIdx.x;
    const int t = threadIdx.x;
    const int n0 = p << PART_SHIFT;
    const int start = p * PCAP;
    const int endp = start + pcnt[p];

    __shared__ int hist[256];
    __shared__ int base[256];
    __shared__ int wsum[4];
    hist[t] = 0;
    __syncthreads();
    for (int i = start + t; i < endp; i += 256)
        atomicAdd(&hist[(pbuf[i] >> 16) & 255], 1);
    __syncthreads();
    int x = hist[t];
    int incl = block_incl_scan_256(x, wsum);
    base[t] = start + incl - x;
    int n = n0 + t;
    if (n < N_NODES) { rp[n] = base[t]; rpe[n] = base[t] + x; }
    hist[t] = 0;
    __syncthreads();
    for (int i = start + t; i < endp; i += 256) {
        unsigned c = pbuf[i];
        int local = (c >> 16) & 255;
        int pos = base[local] + atomicAdd(&hist[local], 1);
        csr16[pos] = (unsigned short)(c & 0xffffu);
    }
}

// ---- MFMA GEMM (r14): h = X @ W; W^T in 32KB LDS; A-frags direct; shfl s/d ----
template<int H, bool IN32>
__global__ __launch_bounds__(256) void gemm_mfma_k(
    const void* __restrict__ Xin, const unsigned short* __restrict__ Wt,
    unsigned short* __restrict__ Hb, int nrows,
    const float* __restrict__ a_src, const float* __restrict__ a_dst,
    float* __restrict__ sb, float* __restrict__ db)
{
    __shared__ unsigned short Wts[128 * 128];
    const int t = threadIdx.x;
    const int row0 = blockIdx.x * 128;

    {
        const uint4* wv = (const uint4*)Wt;
        #pragma unroll
        for (int i = 0; i < 8; ++i) {
            int g = t + 256 * i;
            int n = g >> 4, c = g & 15;
            *(uint4*)&Wts[n * 128 + ((c ^ (n & 7)) << 3)] = wv[g];
        }
    }
    __syncthreads();

    const int lane = t & 63;
    const int w = t >> 6;
    const int lr = lane & 15;
    const int lk = lane >> 4;

    f32x4 acc[2][8];
    #pragma unroll
    for (int rf = 0; rf < 2; ++rf)
        #pragma unroll
        for (int cf = 0; cf < 8; ++cf)
            acc[rf][cf] = (f32x4)(0.f);

    int arow[2];
    #pragma unroll
    for (int rf = 0; rf < 2; ++rf) {
        int r = row0 + w * 32 + rf * 16 + lr;
        arow[rf] = r < nrows ? r : nrows - 1;
    }

    #pragma unroll
    for (int ks = 0; ks < 4; ++ks) {
        bf16x8 av[2], bv[8];
        #pragma unroll
        for (int rf = 0; rf < 2; ++rf) {
            if (IN32) {
                const float* Xf = (const float*)Xin;
                float4 f0 = *(const float4*)(Xf + (size_t)arow[rf] * 128 + (ks * 4 + lk) * 8);
                float4 f1 = *(const float4*)(Xf + (size_t)arow[rf] * 128 + (ks * 4 + lk) * 8 + 4);
                unsigned u0 = pack_bf16(f0.x, f0.y), u1 = pack_bf16(f0.z, f0.w);
                unsigned u2 = pack_bf16(f1.x, f1.y), u3 = pack_bf16(f1.z, f1.w);
                uint4 uu = make_uint4(u0, u1, u2, u3);
                av[rf] = *(bf16x8*)&uu;
            } else {
                const unsigned short* Xb = (const unsigned short*)Xin;
                av[rf] = *(const bf16x8*)(Xb + (size_t)arow[rf] * 128 + (ks * 4 + lk) * 8);
            }
        }
        #pragma unroll
        for (int cf = 0; cf < 8; ++cf) {
            int col = cf * 16 + lr;
            bv[cf] = *(const bf16x8*)&Wts[col * 128 + (((ks * 4 + lk) ^ (col & 7)) << 3)];
        }
        #pragma unroll
        for (int rf = 0; rf < 2; ++rf)
            #pragma unroll
            for (int cf = 0; cf < 8; ++cf)
                acc[rf][cf] = __builtin_amdgcn_mfma_f32_16x16x32_bf16(
                    av[rf], bv[cf], acc[rf][cf], 0, 0, 0);
    }

    float asv[8], adv[8];
    #pragma unroll
    for (int cf = 0; cf < 8; ++cf) {
        asv[cf] = a_src[cf * 16 + lr];
        adv[cf] = a_dst[cf * 16 + lr];
    }
    #pragma unroll
    for (int rf = 0; rf < 2; ++rf) {
        #pragma unroll
        for (int reg = 0; reg < 4; ++reg) {
            const int gr = row0 + w * 32 + rf * 16 + lk * 4 + reg;
            const bool ok = gr < nrows;
            if (ok) {
                #pragma unroll
                for (int cf = 0; cf < 8; ++cf)
                    Hb[(size_t)gr * 128 + cf * 16 + lr] = bf16r(acc[rf][cf][reg]);
            }
            if (H == 4) {
                float ps[4] = {0.f, 0.f, 0.f, 0.f};
                float pd[4] = {0.f, 0.f, 0.f, 0.f};
                #pragma unroll
                for (int cf = 0; cf < 8; ++cf) {
                    ps[cf >> 1] = fmaf(acc[rf][cf][reg], asv[cf], ps[cf >> 1]);
                    pd[cf >> 1] = fmaf(acc[rf][cf][reg], adv[cf], pd[cf >> 1]);
                }
                #pragma unroll
                for (int off = 1; off < 16; off <<= 1)
                    #pragma unroll
                    for (int h = 0; h < 4; ++h) {
                        ps[h] += __shfl_xor(ps[h], off, 64);
                        pd[h] += __shfl_xor(pd[h], off, 64);
                    }
                if (ok && lr < 4) {
                    float sv = lr == 0 ? ps[0] : lr == 1 ? ps[1] : lr == 2 ? ps[2] : ps[3];
                    float dv = lr == 0 ? pd[0] : lr == 1 ? pd[1] : lr == 2 ? pd[2] : pd[3];
                    sb[gr * 4 + lr] = sv;
                    db[gr * 4 + lr] = dv;
                }
            } else {
                float ps = 0.f, pd = 0.f;
                #pragma unroll
                for (int cf = 0; cf < 8; ++cf) {
                    ps = fmaf(acc[rf][cf][reg], asv[cf], ps);
                    pd = fmaf(acc[rf][cf][reg], adv[cf], pd);
                }
                #pragma unroll
                for (int off = 1; off < 16; off <<= 1) {
                    ps += __shfl_xor(ps, off, 64);
                    pd += __shfl_xor(pd, off, 64);
                }
                if (ok && lr == 0) { sb[gr] = ps; db[gr] = pd; }
            }
        }
    }
}

// ============ fused per-destination GAT aggregation ============
// ONE WAVE PER NODE, zero barriers. 4-wide-unrolled gather main loop.
template<int H, bool RELU, bool OUTB>
__global__ __launch_bounds__(256) void gat_fused_k(
    const int* __restrict__ rp, const int* __restrict__ rpe,
    const unsigned short* __restrict__ csr16,
    const unsigned short* __restrict__ Hb, const float* __restrict__ sb,
    const float* __restrict__ db, const float* __restrict__ bias,
    void* __restrict__ outv)
{
    constexpr int C = 128 / H;
    const int lane = threadIdx.x & 63;
    const int n = blockIdx.x * 4 + (threadIdx.x >> 6);
    if (n >= N_NODES) return;
    const int beg = rp[n], end = rpe[n];
    const int deg = end - beg;

    const int f    = lane & 15;
    const int slot = lane >> 4;
    const int hf   = (f * 8) / C;

    float dn[H];
    #pragma unroll
    for (int h = 0; h < H; ++h) dn[h] = db[n * H + h];

    float a0=0.f,a1=0.f,a2=0.f,a3=0.f,a4=0.f,a5=0.f,a6=0.f,a7=0.f;
    float den = 0.f;

    if (deg <= 64) {
        const bool act = lane < deg;
        int s = 0;
        if (act) s = csr16[beg + lane];
        float v[H];
        if (H == 4) {
            float4 s4 = ((const float4*)sb)[s];
            v[0] = lrelu(s4.x + dn[0]); v[1] = lrelu(s4.y + dn[1]);
            v[2] = lrelu(s4.z + dn[2]); v[3] = lrelu(s4.w + dn[3]);
        } else {
            v[0] = lrelu(sb[s] + dn[0]);
        }
        float mh[H];
        #pragma unroll
        for (int h = 0; h < H; ++h) mh[h] = act ? v[h] : -3.0e38f;
        #pragma unroll
        for (int off = 32; off >= 1; off >>= 1)
            #pragma unroll
            for (int h = 0; h < H; ++h)
                mh[h] = fmaxf(mh[h], __shfl_xor(mh[h], off, 64));
        float p[H];
        #pragma unroll
        for (int h = 0; h < H; ++h) p[h] = __expf(v[h] - mh[h]);

        const int iters = (deg + 3) >> 2;
        int it = 0;
        for (; it + 4 <= iters; it += 4) {
            const int jj0 = slot + it * 4;
            const int jj1 = jj0 + 4, jj2 = jj0 + 8, jj3 = jj0 + 12;
            const bool on3 = jj3 < deg;
            const int jc3 = on3 ? jj3 : 0;
            int sj0 = __shfl(s, jj0, 64), sj1 = __shfl(s, jj1, 64);
            int sj2 = __shfl(s, jj2, 64), sj3 = __shfl(s, jc3, 64);
            float pj0, pj1, pj2, pj3;
            if (H == 4) {
                float q00=__shfl(p[0],jj0,64), q01=__shfl(p[1],jj0,64), q02=__shfl(p[2],jj0,64), q03=__shfl(p[3],jj0,64);
                float q10=__shfl(p[0],jj1,64), q11=__shfl(p[1],jj1,64), q12=__shfl(p[2],jj1,64), q13=__shfl(p[3],jj1,64);
                float q20=__shfl(p[0],jj2,64), q21=__shfl(p[1],jj2,64), q22=__shfl(p[2],jj2,64), q23=__shfl(p[3],jj2,64);
                float q30=__shfl(p[0],jc3,64), q31=__shfl(p[1],jc3,64), q32=__shfl(p[2],jc3,64), q33=__shfl(p[3],jc3,64);
                pj0 = hf == 0 ? q00 : (hf == 1 ? q01 : (hf == 2 ? q02 : q03));
                pj1 = hf == 0 ? q10 : (hf == 1 ? q11 : (hf == 2 ? q12 : q13));
                pj2 = hf == 0 ? q20 : (hf == 1 ? q21 : (hf == 2 ? q22 : q23));
                pj3 = hf == 0 ? q30 : (hf == 1 ? q31 : (hf == 2 ? q32 : q33));
            } else {
                pj0 = __shfl(p[0], jj0, 64); pj1 = __shfl(p[0], jj1, 64);
                pj2 = __shfl(p[0], jj2, 64); pj3 = __shfl(p[0], jc3, 64);
            }
            pj3 = on3 ? pj3 : 0.f;
            uint4 hv0 = *(const uint4*)(Hb + (size_t)sj0 * 128 + f * 8);
            uint4 hv1 = *(const uint4*)(Hb + (size_t)sj1 * 128 + f * 8);
            uint4 hv2 = *(const uint4*)(Hb + (size_t)sj2 * 128 + f * 8);
            uint4 hv3 = *(const uint4*)(Hb + (size_t)sj3 * 128 + f * 8);
            den += pj0 + pj1 + pj2 + pj3;
            a0 = fmaf(pj0, blo(hv0.x), a0);  a1 = fmaf(pj0, bhi(hv0.x), a1);
            a2 = fmaf(pj0, blo(hv0.y), a2);  a3 = fmaf(pj0, bhi(hv0.y), a3);
            a4 = fmaf(pj0, blo(hv0.z), a4);  a5 = fmaf(pj0, bhi(hv0.z), a5);
            a6 = fmaf(pj0, blo(hv0.w), a6);  a7 = fmaf(pj0, bhi(hv0.w), a7);
            a0 = fmaf(pj1, blo(hv1.x), a0);  a1 = fmaf(pj1, bhi(hv1.x), a1);
            a2 = fmaf(pj1, blo(hv1.y), a2);  a3 = fmaf(pj1, bhi(hv1.y), a3);
            a4 = fmaf(pj1, blo(hv1.z), a4);  a5 = fmaf(pj1, bhi(hv1.z), a5);
            a6 = fmaf(pj1, blo(hv1.w), a6);  a7 = fmaf(pj1, bhi(hv1.w), a7);
            a0 = fmaf(pj2, blo(hv2.x), a0);  a1 = fmaf(pj2, bhi(hv2.x), a1);
            a2 = fmaf(pj2, blo(hv2.y), a2);  a3 = fmaf(pj2, bhi(hv2.y), a3);
            a4 = fmaf(pj2, blo(hv2.z), a4);  a5 = fmaf(pj2, bhi(hv2.z), a5);
            a6 = fmaf(pj2, blo(hv2.w), a6);  a7 = fmaf(pj2, bhi(hv2.w), a7);
            a0 = fmaf(pj3, blo(hv3.x), a0);  a1 = fmaf(pj3, bhi(hv3.x), a1);
            a2 = fmaf(pj3, blo(hv3.y), a2);  a3 = fmaf(pj3, bhi(hv3.y), a3);
            a4 = fmaf(pj3, blo(hv3.z), a4);  a5 = fmaf(pj3, bhi(hv3.z), a5);
            a6 = fmaf(pj3, blo(hv3.w), a6);  a7 = fmaf(pj3, bhi(hv3.w), a7);
        }
        for (; it < iters; ++it) {
            const int jj = slot + it * 4;
            const bool on = jj < deg;
            const int jc = on ? jj : 0;
            int sj = __shfl(s, jc, 64);
            float pj;
            if (H == 4) {
                float q0 = __shfl(p[0], jc, 64);
                float q1 = __shfl(p[1], jc, 64);
                float q2 = __shfl(p[2], jc, 64);
                float q3 = __shfl(p[3], jc, 64);
                pj = hf == 0 ? q0 : (hf == 1 ? q1 : (hf == 2 ? q2 : q3));
            } else {
                pj = __shfl(p[0], jc, 64);
            }
            pj = on ? pj : 0.f;
            den += pj;
            uint4 hv = *(const uint4*)(Hb + (size_t)sj * 128 + f * 8);
            a0 = fmaf(pj, blo(hv.x), a0);  a1 = fmaf(pj, bhi(hv.x), a1);
            a2 = fmaf(pj, blo(hv.y), a2);  a3 = fmaf(pj, bhi(hv.y), a3);
            a4 = fmaf(pj, blo(hv.z), a4);  a5 = fmaf(pj, bhi(hv.z), a5);
            a6 = fmaf(pj, blo(hv.w), a6);  a7 = fmaf(pj, bhi(hv.w), a7);
        }
    } else {
        float mh[H];
        #pragma unroll
        for (int h = 0; h < H; ++h) mh[h] = -3.0e38f;
        for (int i = beg + lane; i < end; i += 64) {
            int s = csr16[i];
            if (H == 4) {
                float4 s4 = ((const float4*)sb)[s];
                mh[0] = fmaxf(mh[0], lrelu(s4.x + dn[0]));
                mh[1] = fmaxf(mh[1], lrelu(s4.y + dn[1]));
                mh[2] = fmaxf(mh[2], lrelu(s4.z + dn[2]));
                mh[3] = fmaxf(mh[3], lrelu(s4.w + dn[3]));
            } else {
                mh[0] = fmaxf(mh[0], lrelu(sb[s] + dn[0]));
            }
        }
        #pragma unroll
        for (int off = 32; off >= 1; off >>= 1)
            #pragma unroll
            for (int h = 0; h < H; ++h)
                mh[h] = fmaxf(mh[h], __shfl_xor(mh[h], off, 64));
        float mhf = (H == 1) ? mh[0]
                  : (hf == 0 ? mh[0] : hf == 1 ? mh[1] : hf == 2 ? mh[2] : mh[3]);
        float dnf = (H == 1) ? dn[0]
                  : (hf == 0 ? dn[0] : hf == 1 ? dn[1] : hf == 2 ? dn[2] : dn[3]);
        for (int jj = slot; jj < deg; jj += 4) {
            int sj = csr16[beg + jj];
            float pj = __expf(lrelu(sb[sj * H + hf] + dnf) - mhf);
            den += pj;
            uint4 hv = *(const uint4*)(Hb + (size_t)sj * 128 + f * 8);
            a0 = fmaf(pj, blo(hv.x), a0);  a1 = fmaf(pj, bhi(hv.x), a1);
            a2 = fmaf(pj, blo(hv.y), a2);  a3 = fmaf(pj, bhi(hv.y), a3);
            a4 = fmaf(pj, blo(hv.z), a4);  a5 = fmaf(pj, bhi(hv.z), a5);
            a6 = fmaf(pj, blo(hv.w), a6);  a7 = fmaf(pj, bhi(hv.w), a7);
        }
    }

    #pragma unroll
    for (int off = 16; off < 64; off <<= 1) {
        a0 += __shfl_xor(a0, off, 64); a1 += __shfl_xor(a1, off, 64);
        a2 += __shfl_xor(a2, off, 64); a3 += __shfl_xor(a3, off, 64);
        a4 += __shfl_xor(a4, off, 64); a5 += __shfl_xor(a5, off, 64);
        a6 += __shfl_xor(a6, off, 64); a7 += __shfl_xor(a7, off, 64);
        den += __shfl_xor(den, off, 64);
    }
    if (lane < 16) {
        float inv = 1.f / (den + EPS_V);
        float4 ba = *(const float4*)(bias + f * 8);
        float4 bb = *(const float4*)(bias + f * 8 + 4);
        float o0 = a0 * inv + ba.x, o1 = a1 * inv + ba.y;
        float o2 = a2 * inv + ba.z, o3 = a3 * inv + ba.w;
        float o4 = a4 * inv + bb.x, o5 = a5 * inv + bb.y;
        float o6 = a6 * inv + bb.z, o7 = a7 * inv + bb.w;
        if (RELU) {
            o0 = fmaxf(o0, 0.f); o1 = fmaxf(o1, 0.f);
            o2 = fmaxf(o2, 0.f); o3 = fmaxf(o3, 0.f);
            o4 = fmaxf(o4, 0.f); o5 = fmaxf(o5, 0.f);
            o6 = fmaxf(o6, 0.f); o7 = fmaxf(o7, 0.f);
        }
        if (OUTB) {
            unsigned short* ob = (unsigned short*)outv;
            uint4 u;
            u.x = pack_bf16(o0, o1); u.y = pack_bf16(o2, o3);
            u.z = pack_bf16(o4, o5); u.w = pack_bf16(o6, o7);
            *(uint4*)(ob + (size_t)n * 128 + f * 8) = u;
        } else {
            float* op = (float*)outv + (size_t)n * 128 + f * 8;
            *(float4*)(op)     = make_float4(o0, o1, o2, o3);
            *(float4*)(op + 4) = make_float4(o4, o5, o6, o7);
        }
    }
}

template<int H, bool IN32, bool RELU, bool OUTB>
void run_layer(const void* xin, const unsigned short* Wt,
               const float* as_, const float* ad_, const float* bias,
               const int* rp, const int* rpe, const unsigned short* csr16,
               unsigned short* hbuf, void* outv, float* sb, float* db,
               hipStream_t stream)
{
    gemm_mfma_k<H, IN32><<<(N_NODES + 127) / 128, 256, 0, stream>>>(
        xin, Wt, hbuf, N_NODES, as_, ad_, sb, db);
    gat_fused_k<H, RELU, OUTB><<<(N_NODES + 3) / 4, 256, 0, stream>>>(
        rp, rpe, csr16, hbuf, sb, db, bias, outv);
}

} // namespace

extern "C" void kernel_launch(void* const* d_in, const int* in_sizes, int n_in,
                              void* d_out, int out_size, void* d_ws, size_t ws_size,
                              hipStream_t stream)
{
    (void)in_sizes; (void)n_in; (void)out_size; (void)ws_size;
    const float* x   = (const float*)d_in[0];
    const int*   ei  = (const int*)d_in[1];
    const float* W0  = (const float*)d_in[2];
    const float* as0 = (const float*)d_in[3];
    const float* ad0 = (const float*)d_in[4];
    const float* b0  = (const float*)d_in[5];
    const float* W1  = (const float*)d_in[6];
    const float* as1 = (const float*)d_in[7];
    const float* ad1 = (const float*)d_in[8];
    const float* b1  = (const float*)d_in[9];
    const float* W2  = (const float*)d_in[10];
    const float* as2 = (const float*)d_in[11];
    const float* ad2 = (const float*)d_in[12];
    const float* b2  = (const float*)d_in[13];
    float* out = (float*)d_out;

    char* p = (char*)d_ws;
    unsigned short* Hb  = (unsigned short*)p; p += (size_t)N_NODES * 128 * 2;  // bf16 h
    unsigned short* Xb1 = (unsigned short*)p; p += (size_t)N_NODES * 128 * 2;  // bf16 x1
    unsigned short* Xb2 = (unsigned short*)p; p += (size_t)N_NODES * 128 * 2;  // bf16 x2
    unsigned short* Wt0 = (unsigned short*)p; p += 128 * 128 * 2;
    unsigned short* Wt1 = (unsigned short*)p; p += 128 * 128 * 2;
    unsigned short* Wt2 = (unsigned short*)p; p += 128 * 128 * 2;
    float* sb      = (float*)p;  p += (size_t)N_NODES * 4 * 4;
    float* db      = (float*)p;  p += (size_t)N_NODES * 4 * 4;
    int*   rp      = (int*)p;    p += (size_t)N_NODES * 4;
    int*   rpe     = (int*)p;    p += (size_t)N_NODES * 4;
    int*   pcnt    = (int*)p;    p += (size_t)NPART * 4;
    unsigned* pbuf = (unsigned*)p; p += (size_t)NPART * PCAP * 4;
    unsigned short* csr16 = (unsigned short*)p; p += (size_t)NPART * PCAP * 2;

    // ---- one-time prep: merged {W transpose | partition scatter}, then CSR ----
    hipMemsetAsync(pcnt, 0, (size_t)NPART * 4, stream);
    prep_k<<<3 + NB_S1, 256, 0, stream>>>(W0, W1, W2, Wt0, Wt1, Wt2, ei, pcnt, pbuf);
    part_to_csr2_k<<<NPART, 256, 0, stream>>>(pcnt, pbuf, rp, rpe, csr16);

    // Layer 0: x(fp32 direct) -> h(Hb); agg -> Xb1 (bf16, ReLU)
    run_layer<4, true,  true,  true >(x,   Wt0, as0, ad0, b0, rp, rpe, csr16, Hb, Xb1, sb, db, stream);
    // Layer 1: Xb1 -> h(Hb); agg -> Xb2 (bf16, ReLU)
    run_layer<4, false, true,  true >(Xb1, Wt1, as1, ad1, b1, rp, rpe, csr16, Hb, Xb2, sb, db, stream);
    // Layer 2 (H=1): Xb2 -> h(Hb); agg -> out (fp32, no ReLU)
    run_layer<1, false, false, false>(Xb2, Wt2, as2, ad2, b2, rp, rpe, csr16, Hb, out, sb, db, stream);
}